// Round 1
// baseline (34380.841 us; speedup 1.0000x reference)
//
#include <hip/hip_runtime.h>
#include <math.h>

#define HD 512
#define NB 32
#define LS 2048
#define SYNC_OFF (65536 + 3 * HD * HD)  // float offset of sync area in ws

typedef unsigned long long ull;

__device__ __forceinline__ float2 u2f(ull u) { return __builtin_bit_cast(float2, u); }

// ---------------------------------------------------------------------------
// Kernel 1 (unchanged, known-good): Xi = x @ Wi0 + bi0 into d_out's [B,L,H].
// ---------------------------------------------------------------------------
__global__ __launch_bounds__(256) void xi_gemm(const float* __restrict__ x,
                                               const float* __restrict__ Wi0,
                                               const float* __restrict__ bi0,
                                               float* __restrict__ out) {
  __shared__ float As[16][68];
  __shared__ float Bs[16][68];
  const int bn = blockIdx.x * 64;
  const int bm = blockIdx.y * 64;
  const int tid = threadIdx.x;
  const int tm = (tid & 15) * 4;
  const int tn = (tid >> 4) * 4;
  float acc[4][4] = {};
  for (int k0 = 0; k0 < HD; k0 += 16) {
    {
      const int r = tid >> 2, ks = (tid & 3) * 4;
      const float4 av = *(const float4*)(x + (size_t)(bm + r) * HD + k0 + ks);
      As[ks + 0][r] = av.x; As[ks + 1][r] = av.y;
      As[ks + 2][r] = av.z; As[ks + 3][r] = av.w;
      const int kk = tid >> 4, ns = (tid & 15) * 4;
      *(float4*)&Bs[kk][ns] = *(const float4*)(Wi0 + (size_t)(k0 + kk) * HD + bn + ns);
    }
    __syncthreads();
#pragma unroll
    for (int k = 0; k < 16; ++k) {
      const float4 a = *(const float4*)&As[k][tm];
      const float4 b = *(const float4*)&Bs[k][tn];
      acc[0][0] = fmaf(a.x, b.x, acc[0][0]); acc[0][1] = fmaf(a.x, b.y, acc[0][1]);
      acc[0][2] = fmaf(a.x, b.z, acc[0][2]); acc[0][3] = fmaf(a.x, b.w, acc[0][3]);
      acc[1][0] = fmaf(a.y, b.x, acc[1][0]); acc[1][1] = fmaf(a.y, b.y, acc[1][1]);
      acc[1][2] = fmaf(a.y, b.z, acc[1][2]); acc[1][3] = fmaf(a.y, b.w, acc[1][3]);
      acc[2][0] = fmaf(a.z, b.x, acc[2][0]); acc[2][1] = fmaf(a.z, b.y, acc[2][1]);
      acc[2][2] = fmaf(a.z, b.z, acc[2][2]); acc[2][3] = fmaf(a.z, b.w, acc[2][3]);
      acc[3][0] = fmaf(a.w, b.x, acc[3][0]); acc[3][1] = fmaf(a.w, b.y, acc[3][1]);
      acc[3][2] = fmaf(a.w, b.z, acc[3][2]); acc[3][3] = fmaf(a.w, b.w, acc[3][3]);
    }
    __syncthreads();
  }
  const float4 bias = *(const float4*)(bi0 + bn + tn);
#pragma unroll
  for (int i = 0; i < 4; ++i) {
    float4 v;
    v.x = acc[i][0] + bias.x; v.y = acc[i][1] + bias.y;
    v.z = acc[i][2] + bias.z; v.w = acc[i][3] + bias.w;
    *(float4*)(out + (size_t)(bm + tm + i) * HD + bn + tn) = v;
  }
}

// ---------------------------------------------------------------------------
// Kernel 2 (unchanged): WT[z][c][k] = W_z[k][c], z in {Wh0, Wi1, Wh1}.
// ---------------------------------------------------------------------------
__global__ void transpose_w(const float* __restrict__ Wh0,
                            const float* __restrict__ Wi1,
                            const float* __restrict__ Wh1,
                            float* __restrict__ WT) {
  const int k = blockIdx.y;
  const int c = (blockIdx.x << 8) + threadIdx.x;
  const int z = blockIdx.z;
  const float* src = (z == 0) ? Wh0 : (z == 1) ? Wi1 : Wh1;
  WT[(size_t)z * HD * HD + (size_t)c * HD + k] = src[(size_t)k * HD + c];
}

// ---------------------------------------------------------------------------
// Kernel 3 (unchanged): init h dbufs (parity 1 = h[-1]) + zero sync area
// (now 256 per-block progress stamps instead of 2 barrier counters).
// ---------------------------------------------------------------------------
__global__ void init_h(const float* __restrict__ h0, float* __restrict__ ws) {
  const int i = blockIdx.x * 256 + threadIdx.x;  // [0, 32768)
  const float v = h0[i];
  if (i < 16384) ws[16384 + i] = v;                   // layer 0, parity 1
  else           ws[32768 + 16384 + (i - 16384)] = v; // layer 1, parity 1
  if (blockIdx.x == 0) {
    unsigned* syncp = (unsigned*)(ws + SYNC_OFF);
    syncp[threadIdx.x] = 0;
  }
}

// ---------------------------------------------------------------------------
// Per-producer stamp wait (replaces the centralized counter barrier).
// Each producer block owns ONE stamp word: stamp = #steps completed. Plain
// relaxed agent-scope STORES — no atomic RMW serialization at one address,
// which was the dominant per-step cost of the old group_barrier (128 same-
// line fetch_adds + 128 polling lane-0s queuing behind them).
// Wave 0 polls: lane l loads stamp a[l] and b[l] (2 coalesced wave-loads over
// 8 cache lines), exits when __all(a>=ta && b>=tb). Ordering chain is the
// same one the old kernel relied on: producers' sc1 h-stores are drained by
// __syncthreads' vmcnt(0) BEFORE the stamp store is issued, and consumers'
// sc1 h-loads are issued only after the poll load returns the new stamp.
// ---------------------------------------------------------------------------
__device__ __forceinline__ void stamp_wait(const unsigned* a, int ta,
                                           const unsigned* b, int tb) {
  if (threadIdx.x < 64) {
    for (;;) {
      const int sa = (int)__hip_atomic_load(a + threadIdx.x, __ATOMIC_RELAXED,
                                            __HIP_MEMORY_SCOPE_AGENT);
      const int sb = (int)__hip_atomic_load(b + threadIdx.x, __ATOMIC_RELAXED,
                                            __HIP_MEMORY_SCOPE_AGENT);
      if (__all(sa >= ta && sb >= tb)) break;
      __builtin_amdgcn_s_sleep(1);
    }
  }
  __syncthreads();
}

// ---------------------------------------------------------------------------
// Kernel 4: persistent pipelined recurrence. Compute structure identical to
// the proven round-3 kernel; only the synchronization changed:
//   stamp[L0][g][cb] >= t   <=> h0[t-1] fully published by layer-0 group g
//   stamp[L1][g][cb] >= t   <=> h1[t-1] published AND h0[t-1] consumed
// L0 step t waits: own >= t, L1 >= t-1 (safe to overwrite h0[t-2]).
// L1 step t waits: L0 >= t+1 (h0[t] ready; also orders L0's Xi[t] read
// before L1's out[b,t,:] overwrite), own >= t.
// Progress induction: (all L0>=t, all L1>=t-1) lets every block advance.
// The two g-groups (batch halves) are fully independent.
// ---------------------------------------------------------------------------
__global__ __launch_bounds__(256, 1) void rnn_persist(
    const float* __restrict__ WT,
    const float* __restrict__ bh0,
    const float* __restrict__ bi1,
    const float* __restrict__ bh1,
    float* __restrict__ outbuf,
    float* __restrict__ ws) {
  __shared__ float part[128 * 36];

  const int tid = threadIdx.x;
  const int bid = blockIdx.x;
  const int g = bid & 1;
  const int layer = (bid >> 1) & 1;
  const int cb = bid >> 2;          // [0,64)
  const int col0 = cb * 8;
  const int bbase = g * 16;

  float* h0b = ws;
  float* h1b = ws + 32768;
  unsigned* syncp = (unsigned*)(ws + SYNC_OFF);
  unsigned* stampL0 = syncp + g * 64;        // 64 stamps, layer-0 group g
  unsigned* stampL1 = syncp + 128 + g * 64;  // 64 stamps, layer-1 group g
  const size_t OUT0 = (size_t)NB * LS * HD;

  const int fco = tid & 7;
  const int fbo = tid >> 3;         // [0,16)
  const int fcol = col0 + fco;
  const int fb = bbase + fbo;

  if (layer == 0) {
    const int cg = tid & 1;                 // 2 col-groups of 4
    const int ks = (tid >> 1) & 15;         // 16 k-slices of 32
    const int kb = ks * 32;
    const int bg = tid >> 5;                // 8 b-groups of 2
    float4 w[4][8];
#pragma unroll
    for (int ci = 0; ci < 4; ++ci)
#pragma unroll
      for (int kk = 0; kk < 8; ++kk)
        w[ci][kk] = *(const float4*)(WT + (size_t)(col0 + cg * 4 + ci) * HD + kb + kk * 4);
    float fbias = 0.f;
    if (tid < 128) fbias = bh0[fcol];

    for (int t = 0; t < LS; ++t) {
      // Prefetch Xi[t] BEFORE the wait so its latency hides under polling.
      // Safe vs L1's out[b,t,:] overwrite: L1 step t requires L0 stamps>=t+1,
      // and our stamp t+1 is stored only after xi's value is consumed.
      float xi = 0.f;
      if (tid < 128) xi = outbuf[((size_t)fb * LS + t) * HD + fcol];

      stamp_wait(stampL0, t, stampL1, t - 1);

      ull* hs = (ull*)(h0b + ((t + 1) & 1) * 16384 + (size_t)(bbase + bg * 2) * HD + kb);
      ull hau[16], hbu[16];
#pragma unroll
      for (int j = 0; j < 16; ++j)
        hau[j] = __hip_atomic_load(hs + j, __ATOMIC_RELAXED, __HIP_MEMORY_SCOPE_AGENT);
#pragma unroll
      for (int j = 0; j < 16; ++j)
        hbu[j] = __hip_atomic_load(hs + 256 + j, __ATOMIC_RELAXED, __HIP_MEMORY_SCOPE_AGENT);
      float acc[4][2] = {};
#pragma unroll
      for (int kk = 0; kk < 8; ++kk) {
        const float2 a0 = u2f(hau[2 * kk]), a1 = u2f(hau[2 * kk + 1]);
        const float2 b0 = u2f(hbu[2 * kk]), b1 = u2f(hbu[2 * kk + 1]);
#pragma unroll
        for (int ci = 0; ci < 4; ++ci) {
          const float4 wv = w[ci][kk];
          acc[ci][0] = fmaf(wv.x, a0.x, acc[ci][0]);
          acc[ci][0] = fmaf(wv.y, a0.y, acc[ci][0]);
          acc[ci][0] = fmaf(wv.z, a1.x, acc[ci][0]);
          acc[ci][0] = fmaf(wv.w, a1.y, acc[ci][0]);
          acc[ci][1] = fmaf(wv.x, b0.x, acc[ci][1]);
          acc[ci][1] = fmaf(wv.y, b0.y, acc[ci][1]);
          acc[ci][1] = fmaf(wv.z, b1.x, acc[ci][1]);
          acc[ci][1] = fmaf(wv.w, b1.y, acc[ci][1]);
        }
      }
#pragma unroll
      for (int ci = 0; ci < 4; ++ci)
#pragma unroll
        for (int bj = 0; bj < 2; ++bj)
          part[((bg * 2 + bj) * 8 + cg * 4 + ci) * 36 + ks] = acc[ci][bj];
      __syncthreads();
      if (tid < 128) {
        const float4* pp = (const float4*)&part[tid * 36];
        const float4 p0 = pp[0], p1 = pp[1], p2 = pp[2], p3 = pp[3];
        float s = (((p0.x + p0.y) + (p0.z + p0.w)) + ((p1.x + p1.y) + (p1.z + p1.w)))
                + (((p2.x + p2.y) + (p2.z + p2.w)) + ((p3.x + p3.y) + (p3.z + p3.w)))
                + xi + fbias;
        const float hv = tanhf(s);
        __hip_atomic_store((unsigned*)(h0b + (t & 1) * 16384 + (size_t)fb * HD + fcol),
                           __builtin_bit_cast(unsigned, hv),
                           __ATOMIC_RELAXED, __HIP_MEMORY_SCOPE_AGENT);
        if (t == LS - 1) outbuf[OUT0 + (size_t)fb * HD + fcol] = hv;  // h_final L0
      }
      // __syncthreads emits s_waitcnt vmcnt(0) per wave before s_barrier:
      // all h stores of this block are at the coherent point before the
      // stamp store below is issued.
      __syncthreads();
      if (tid == 0)
        __hip_atomic_store(stampL0 + cb, (unsigned)(t + 1),
                           __ATOMIC_RELAXED, __HIP_MEMORY_SCOPE_AGENT);
    }
  } else {
    const int m = tid >> 7;                 // 0 = Wi1 (reads h0), 1 = Wh1 (reads h1)
    const int r = tid & 127;
    const int cg = r & 1;
    const int ks = (r >> 1) & 15;
    const int kb = ks * 32;
    const int bg = r >> 5;                  // 4 b-groups of 4
    float4 w[4][8];
    const float* Wm = WT + (size_t)(1 + m) * HD * HD;
#pragma unroll
    for (int ci = 0; ci < 4; ++ci)
#pragma unroll
      for (int kk = 0; kk < 8; ++kk)
        w[ci][kk] = *(const float4*)(Wm + (size_t)(col0 + cg * 4 + ci) * HD + kb + kk * 4);
    float fbias = 0.f;
    if (tid < 128) fbias = bi1[fcol] + bh1[fcol];

    for (int t = 0; t < LS; ++t) {
      stamp_wait(stampL0, t + 1, stampL1, t);

      float* hsrc = (m == 0)
          ? h0b + (t & 1) * 16384           // h0[t]
          : h1b + ((t + 1) & 1) * 16384;    // h1[t-1]
      float acc[4][4] = {};
#pragma unroll
      for (int bj = 0; bj < 4; ++bj) {
        ull* hp = (ull*)(hsrc + (size_t)(bbase + bg * 4 + bj) * HD + kb);
        ull hu[16];
#pragma unroll
        for (int j = 0; j < 16; ++j)
          hu[j] = __hip_atomic_load(hp + j, __ATOMIC_RELAXED, __HIP_MEMORY_SCOPE_AGENT);
#pragma unroll
        for (int kk = 0; kk < 8; ++kk) {
          const float2 h0_ = u2f(hu[2 * kk]), h1_ = u2f(hu[2 * kk + 1]);
#pragma unroll
          for (int ci = 0; ci < 4; ++ci) {
            const float4 wv = w[ci][kk];
            acc[ci][bj] = fmaf(wv.x, h0_.x, acc[ci][bj]);
            acc[ci][bj] = fmaf(wv.y, h0_.y, acc[ci][bj]);
            acc[ci][bj] = fmaf(wv.z, h1_.x, acc[ci][bj]);
            acc[ci][bj] = fmaf(wv.w, h1_.y, acc[ci][bj]);
          }
        }
      }
#pragma unroll
      for (int ci = 0; ci < 4; ++ci)
#pragma unroll
        for (int bj = 0; bj < 4; ++bj)
          part[((bg * 4 + bj) * 8 + cg * 4 + ci) * 36 + m * 16 + ks] = acc[ci][bj];
      __syncthreads();
      if (tid < 128) {
        const float4* pp = (const float4*)&part[tid * 36];
        float s = fbias;
#pragma unroll
        for (int j = 0; j < 8; ++j) {
          const float4 p = pp[j];
          s += ((p.x + p.y) + (p.z + p.w));
        }
        const float hv = tanhf(s);
        __hip_atomic_store((unsigned*)(h1b + (t & 1) * 16384 + (size_t)fb * HD + fcol),
                           __builtin_bit_cast(unsigned, hv),
                           __ATOMIC_RELAXED, __HIP_MEMORY_SCOPE_AGENT);
        outbuf[((size_t)fb * LS + t) * HD + fcol] = hv;
        if (t == LS - 1) outbuf[OUT0 + NB * HD + (size_t)fb * HD + fcol] = hv;  // h_final L1
      }
      __syncthreads();
      if (tid == 0)
        __hip_atomic_store(stampL1 + cb, (unsigned)(t + 1),
                           __ATOMIC_RELAXED, __HIP_MEMORY_SCOPE_AGENT);
    }
  }
}

// ---------------------------------------------------------------------------
// ws layout (floats): [0,65536) h dbufs; [65536,65536+786432) WT;
// [SYNC_OFF, SYNC_OFF+256) per-block progress stamps (u32).
// ---------------------------------------------------------------------------
extern "C" void kernel_launch(void* const* d_in, const int* in_sizes, int n_in,
                              void* d_out, int out_size, void* d_ws, size_t ws_size,
                              hipStream_t stream) {
  const float* x  = (const float*)d_in[0];
  const float* h0 = (const float*)d_in[1];
  const float* Wi = (const float*)d_in[2];
  const float* bi = (const float*)d_in[3];
  const float* Wh = (const float*)d_in[4];
  const float* bh = (const float*)d_in[5];
  float* out = (float*)d_out;
  float* ws  = (float*)d_ws;

  const float* Wi0 = Wi;
  const float* Wi1 = Wi + (size_t)HD * HD;
  const float* bi0 = bi;
  const float* bi1 = bi + HD;
  const float* Wh0 = Wh;
  const float* Wh1 = Wh + (size_t)HD * HD;
  const float* bh0 = bh;
  const float* bh1 = bh + HD;

  const float* WT = ws + 65536;

  xi_gemm<<<dim3(8, 1024), 256, 0, stream>>>(x, Wi0, bi0, out);
  transpose_w<<<dim3(2, 512, 3), 256, 0, stream>>>(Wh0, Wi1, Wh1, ws + 65536);
  init_h<<<128, 256, 0, stream>>>(h0, ws);

  void* kargs[] = {(void*)&WT, (void*)&bh0, (void*)&bi1, (void*)&bh1,
                   (void*)&out, (void*)&ws};
  hipLaunchCooperativeKernel((const void*)rnn_persist, dim3(256), dim3(256),
                             kargs, 0, stream);
}

// Round 2
// 8331.867 us; speedup vs baseline: 4.1264x; 4.1264x over previous
//
#include <hip/hip_runtime.h>
#include <math.h>

#define HD 512
#define NB 32
#define LS 2048
#define SYNC_OFF (65536 + 3 * HD * HD)  // float offset of sync area in ws

// Swizzled LDS h-tile: 16 rows; each row = 16 k-blocks of 32 floats, each
// k-block padded to 36 floats (144 B) so the stride-128B ks read pattern
// spreads across banks (4*(ks+kk) mod 32) instead of a 16-way conflict.
#define HSTRIDE 576                      // floats per LDS h row (16*36)
#define PART_F 4608                      // 128*36 partial floats per sub-block
#define SMEM_FLOATS (2 * PART_F + 2 * 16 * HSTRIDE)  // 9216 + 18432 = 27648
#define SMEM_BYTES (SMEM_FLOATS * 4)                 // 110592

typedef float f32x4 __attribute__((ext_vector_type(4)));

// ---------------------------------------------------------------------------
// Kernel 1 (unchanged, known-good): Xi = x @ Wi0 + bi0 into d_out's [B,L,H].
// ---------------------------------------------------------------------------
__global__ __launch_bounds__(256) void xi_gemm(const float* __restrict__ x,
                                               const float* __restrict__ Wi0,
                                               const float* __restrict__ bi0,
                                               float* __restrict__ out) {
  __shared__ float As[16][68];
  __shared__ float Bs[16][68];
  const int bn = blockIdx.x * 64;
  const int bm = blockIdx.y * 64;
  const int tid = threadIdx.x;
  const int tm = (tid & 15) * 4;
  const int tn = (tid >> 4) * 4;
  float acc[4][4] = {};
  for (int k0 = 0; k0 < HD; k0 += 16) {
    {
      const int r = tid >> 2, ks = (tid & 3) * 4;
      const float4 av = *(const float4*)(x + (size_t)(bm + r) * HD + k0 + ks);
      As[ks + 0][r] = av.x; As[ks + 1][r] = av.y;
      As[ks + 2][r] = av.z; As[ks + 3][r] = av.w;
      const int kk = tid >> 4, ns = (tid & 15) * 4;
      *(float4*)&Bs[kk][ns] = *(const float4*)(Wi0 + (size_t)(k0 + kk) * HD + bn + ns);
    }
    __syncthreads();
#pragma unroll
    for (int k = 0; k < 16; ++k) {
      const float4 a = *(const float4*)&As[k][tm];
      const float4 b = *(const float4*)&Bs[k][tn];
      acc[0][0] = fmaf(a.x, b.x, acc[0][0]); acc[0][1] = fmaf(a.x, b.y, acc[0][1]);
      acc[0][2] = fmaf(a.x, b.z, acc[0][2]); acc[0][3] = fmaf(a.x, b.w, acc[0][3]);
      acc[1][0] = fmaf(a.y, b.x, acc[1][0]); acc[1][1] = fmaf(a.y, b.y, acc[1][1]);
      acc[1][2] = fmaf(a.y, b.z, acc[1][2]); acc[1][3] = fmaf(a.y, b.w, acc[1][3]);
      acc[2][0] = fmaf(a.z, b.x, acc[2][0]); acc[2][1] = fmaf(a.z, b.y, acc[2][1]);
      acc[2][2] = fmaf(a.z, b.z, acc[2][2]); acc[2][3] = fmaf(a.z, b.w, acc[2][3]);
      acc[3][0] = fmaf(a.w, b.x, acc[3][0]); acc[3][1] = fmaf(a.w, b.y, acc[3][1]);
      acc[3][2] = fmaf(a.w, b.z, acc[3][2]); acc[3][3] = fmaf(a.w, b.w, acc[3][3]);
    }
    __syncthreads();
  }
  const float4 bias = *(const float4*)(bi0 + bn + tn);
#pragma unroll
  for (int i = 0; i < 4; ++i) {
    float4 v;
    v.x = acc[i][0] + bias.x; v.y = acc[i][1] + bias.y;
    v.z = acc[i][2] + bias.z; v.w = acc[i][3] + bias.w;
    *(float4*)(out + (size_t)(bm + tm + i) * HD + bn + tn) = v;
  }
}

// ---------------------------------------------------------------------------
// Kernel 2 (unchanged): WT[z][c][k] = W_z[k][c], z in {Wh0, Wi1, Wh1}.
// ---------------------------------------------------------------------------
__global__ void transpose_w(const float* __restrict__ Wh0,
                            const float* __restrict__ Wi1,
                            const float* __restrict__ Wh1,
                            float* __restrict__ WT) {
  const int k = blockIdx.y;
  const int c = (blockIdx.x << 8) + threadIdx.x;
  const int z = blockIdx.z;
  const float* src = (z == 0) ? Wh0 : (z == 1) ? Wi1 : Wh1;
  WT[(size_t)z * HD * HD + (size_t)c * HD + k] = src[(size_t)k * HD + c];
}

// ---------------------------------------------------------------------------
// Kernel 3 (unchanged): init h dbufs (parity 1 = h[-1]) + zero sync area.
// ---------------------------------------------------------------------------
__global__ void init_h(const float* __restrict__ h0, float* __restrict__ ws) {
  const int i = blockIdx.x * 256 + threadIdx.x;  // [0, 32768)
  const float v = h0[i];
  if (i < 16384) ws[16384 + i] = v;                   // layer 0, parity 1
  else           ws[32768 + 16384 + (i - 16384)] = v; // layer 1, parity 1
  if (blockIdx.x == 0) {
    unsigned* syncp = (unsigned*)(ws + SYNC_OFF);
    syncp[threadIdx.x] = 0;
  }
}

// ---------------------------------------------------------------------------
// swz: float4 index [0,2048) of an 8192-float h slice -> swizzled LDS float
// offset. row = idx>>7 (512 floats/row), k-block = (idx&127)>>3, j = idx&7.
// ---------------------------------------------------------------------------
__device__ __forceinline__ int swz(int idx) {
  const int row = idx >> 7, f4 = idx & 127;
  return row * HSTRIDE + (f4 >> 3) * 36 + (f4 & 7) * 4;
}

// Coherent 16B load (sc1 = device-scope, same coherency path the proven
// kernel's agent-relaxed atomic loads used, but 16B wide and coalesced).
// Loads are issued without waits; a single vmcnt(0) fence precedes the LDS
// writes (asm volatile + "memory" clobber orders the ds_writes after it).
#define LDG_C(dst, p) \
  asm volatile("global_load_dwordx4 %0, %1, off sc1" : "=v"(dst) : "v"(p))

__device__ __forceinline__ void stage1(const float* __restrict__ src,
                                       float* dst, int tid) {
  f32x4 a, b, c, d;
  LDG_C(a, src + ((0 * 512 + tid) << 2));
  LDG_C(b, src + ((1 * 512 + tid) << 2));
  LDG_C(c, src + ((2 * 512 + tid) << 2));
  LDG_C(d, src + ((3 * 512 + tid) << 2));
  asm volatile("s_waitcnt vmcnt(0)" ::: "memory");
  *(f32x4*)&dst[swz(0 * 512 + tid)] = a;
  *(f32x4*)&dst[swz(1 * 512 + tid)] = b;
  *(f32x4*)&dst[swz(2 * 512 + tid)] = c;
  *(f32x4*)&dst[swz(3 * 512 + tid)] = d;
}

__device__ __forceinline__ void stage2(const float* __restrict__ s0,
                                       const float* __restrict__ s1,
                                       float* d0, float* d1, int tid) {
  f32x4 a, b, c, d, e, f, g2, h;
  LDG_C(a, s0 + ((0 * 512 + tid) << 2));
  LDG_C(b, s0 + ((1 * 512 + tid) << 2));
  LDG_C(c, s0 + ((2 * 512 + tid) << 2));
  LDG_C(d, s0 + ((3 * 512 + tid) << 2));
  LDG_C(e, s1 + ((0 * 512 + tid) << 2));
  LDG_C(f, s1 + ((1 * 512 + tid) << 2));
  LDG_C(g2, s1 + ((2 * 512 + tid) << 2));
  LDG_C(h, s1 + ((3 * 512 + tid) << 2));
  asm volatile("s_waitcnt vmcnt(0)" ::: "memory");
  *(f32x4*)&d0[swz(0 * 512 + tid)] = a;
  *(f32x4*)&d0[swz(1 * 512 + tid)] = b;
  *(f32x4*)&d0[swz(2 * 512 + tid)] = c;
  *(f32x4*)&d0[swz(3 * 512 + tid)] = d;
  *(f32x4*)&d1[swz(0 * 512 + tid)] = e;
  *(f32x4*)&d1[swz(1 * 512 + tid)] = f;
  *(f32x4*)&d1[swz(2 * 512 + tid)] = g2;
  *(f32x4*)&d1[swz(3 * 512 + tid)] = h;
}

// ---------------------------------------------------------------------------
// Stamp wait: 32 stamps per (layer, group) = one 128B line each (4 hot lines
// total, ~64 polling waves per line at >=12 cyc spacing — off the contention
// cliff). Lanes 0..31 check array a, lanes 32..63 check array b; one wave-
// load per poll round. Consumers' staging loads are data/branch-dependent on
// the poll result, and stamp_wait ends in __syncthreads (compiler fence).
// ---------------------------------------------------------------------------
__device__ __forceinline__ void stamp_wait(const unsigned* a, int ta,
                                           const unsigned* b, int tb) {
  if (threadIdx.x < 64) {
    const int l = threadIdx.x;
    const unsigned* p = (l < 32) ? (a + l) : (b + (l - 32));
    const int tg = (l < 32) ? ta : tb;
    for (;;) {
      const int sv = (int)__hip_atomic_load(p, __ATOMIC_RELAXED,
                                            __HIP_MEMORY_SCOPE_AGENT);
      if (__all(sv >= tg)) break;
      __builtin_amdgcn_s_sleep(1);
    }
  }
  __syncthreads();
}

// ---------------------------------------------------------------------------
// Kernel 4: persistent recurrence, 128 blocks x 512 threads (2 fused
// sub-blocks of the proven 256-thread structure). Per step each block stages
// its group's h slice(s) into LDS ONCE with coalesced 16B sc1 loads (2048
// requests vs 16K fine-grained 8B before — the round-1 bottleneck), then
// computes entirely from LDS.
//   stamp[L0][g][cb2] >= t  <=> h0[t-1] published by that block
//   L0 step t waits: own >= t, L1 >= t-1.  L1 step t: L0 >= t+1, own >= t.
// Same dependency logic/ordering chain as the passing kernels; the own-stamp
// wait also guarantees no block overwrites a buffer another block is still
// staging (writer at t+1 needs ALL own stamps >= t+1 => staging at t done).
// ---------------------------------------------------------------------------
__global__ __launch_bounds__(512, 2) void rnn_persist(
    const float* __restrict__ WT,
    const float* __restrict__ bh0,
    const float* __restrict__ bi1,
    const float* __restrict__ bh1,
    float* __restrict__ outbuf,
    float* __restrict__ ws) {
  extern __shared__ float smem[];

  const int tid = threadIdx.x;
  const int bid = blockIdx.x;
  const int g = bid & 1;
  const int layer = (bid >> 1) & 1;
  const int cb2 = bid >> 2;          // [0,32)
  const int sb = tid >> 8;           // sub-block 0/1
  const int st = tid & 255;
  const int col0 = (cb2 * 2 + sb) * 8;
  const int bbase = g * 16;

  float* part = smem + sb * PART_F;
  float* hst0 = smem + 2 * PART_F;
  float* hst1 = hst0 + 16 * HSTRIDE;

  float* h0b = ws;
  float* h1b = ws + 32768;
  unsigned* syncp = (unsigned*)(ws + SYNC_OFF);
  unsigned* stampL0 = syncp + g * 32;
  unsigned* stampL1 = syncp + 64 + g * 32;
  const size_t OUT0 = (size_t)NB * LS * HD;

  const int fco = st & 7;
  const int fbo = st >> 3;           // [0,16)
  const int fcol = col0 + fco;
  const int fb = bbase + fbo;

  if (layer == 0) {
    const int cg = st & 1;                 // 2 col-groups of 4
    const int ks = (st >> 1) & 15;         // 16 k-slices of 32
    const int kb = ks * 32;
    const int bg = st >> 5;                // 8 b-groups of 2
    float4 w[4][8];
#pragma unroll
    for (int ci = 0; ci < 4; ++ci)
#pragma unroll
      for (int kk = 0; kk < 8; ++kk)
        w[ci][kk] = *(const float4*)(WT + (size_t)(col0 + cg * 4 + ci) * HD + kb + kk * 4);
    float fbias = 0.f;
    if (st < 128) fbias = bh0[fcol];

    for (int t = 0; t < LS; ++t) {
      // Xi prefetch (plain cached load) — hazard-free: L1 overwrites
      // out[b,t,:] only after ALL L0 stamps >= t+1, i.e. after this read.
      float xi = 0.f;
      if (st < 128) xi = outbuf[((size_t)fb * LS + t) * HD + fcol];

      stamp_wait(stampL0, t, stampL1, t - 1);
      stage1(h0b + ((t + 1) & 1) * 16384 + bbase * HD, hst0, tid);
      __syncthreads();

      const float* rA = hst0 + (bg * 2) * HSTRIDE + ks * 36;
      const float* rB = rA + HSTRIDE;
      float acc[4][2] = {};
#pragma unroll
      for (int kk = 0; kk < 8; ++kk) {
        const float4 a4 = *(const float4*)(rA + kk * 4);
        const float4 b4 = *(const float4*)(rB + kk * 4);
#pragma unroll
        for (int ci = 0; ci < 4; ++ci) {
          const float4 wv = w[ci][kk];
          acc[ci][0] = fmaf(wv.x, a4.x, acc[ci][0]);
          acc[ci][0] = fmaf(wv.y, a4.y, acc[ci][0]);
          acc[ci][0] = fmaf(wv.z, a4.z, acc[ci][0]);
          acc[ci][0] = fmaf(wv.w, a4.w, acc[ci][0]);
          acc[ci][1] = fmaf(wv.x, b4.x, acc[ci][1]);
          acc[ci][1] = fmaf(wv.y, b4.y, acc[ci][1]);
          acc[ci][1] = fmaf(wv.z, b4.z, acc[ci][1]);
          acc[ci][1] = fmaf(wv.w, b4.w, acc[ci][1]);
        }
      }
#pragma unroll
      for (int ci = 0; ci < 4; ++ci)
#pragma unroll
        for (int bj = 0; bj < 2; ++bj)
          part[((bg * 2 + bj) * 8 + cg * 4 + ci) * 36 + ks] = acc[ci][bj];
      __syncthreads();
      if (st < 128) {
        const float4* pp = (const float4*)&part[st * 36];
        const float4 p0 = pp[0], p1 = pp[1], p2 = pp[2], p3 = pp[3];
        float sv = (((p0.x + p0.y) + (p0.z + p0.w)) + ((p1.x + p1.y) + (p1.z + p1.w)))
                 + (((p2.x + p2.y) + (p2.z + p2.w)) + ((p3.x + p3.y) + (p3.z + p3.w)))
                 + xi + fbias;
        const float hv = tanhf(sv);
        __hip_atomic_store((unsigned*)(h0b + (t & 1) * 16384 + (size_t)fb * HD + fcol),
                           __builtin_bit_cast(unsigned, hv),
                           __ATOMIC_RELAXED, __HIP_MEMORY_SCOPE_AGENT);
        if (t == LS - 1) outbuf[OUT0 + (size_t)fb * HD + fcol] = hv;  // h_final L0
      }
      // __syncthreads: every wave drains its vmcnt(0) (h sc1 stores at the
      // coherent point) before any wave reaches the stamp store below.
      __syncthreads();
      if (tid == 0)
        __hip_atomic_store(stampL0 + cb2, (unsigned)(t + 1),
                           __ATOMIC_RELAXED, __HIP_MEMORY_SCOPE_AGENT);
    }
  } else {
    const int m = st >> 7;                 // 0 = Wi1 (reads h0), 1 = Wh1 (reads h1)
    const int r = st & 127;
    const int cg = r & 1;
    const int ks = (r >> 1) & 15;
    const int kb = ks * 32;
    const int bg = r >> 5;                 // 4 b-groups of 4
    float4 w[4][8];
    const float* Wm = WT + (size_t)(1 + m) * HD * HD;
#pragma unroll
    for (int ci = 0; ci < 4; ++ci)
#pragma unroll
      for (int kk = 0; kk < 8; ++kk)
        w[ci][kk] = *(const float4*)(Wm + (size_t)(col0 + cg * 4 + ci) * HD + kb + kk * 4);
    float fbias = 0.f;
    if (st < 128) fbias = bi1[fcol] + bh1[fcol];

    for (int t = 0; t < LS; ++t) {
      stamp_wait(stampL0, t + 1, stampL1, t);
      stage2(h0b + (t & 1) * 16384 + bbase * HD,          // h0[t]
             h1b + ((t + 1) & 1) * 16384 + bbase * HD,    // h1[t-1]
             hst0, hst1, tid);
      __syncthreads();

      const float* hbase = (m == 0) ? hst0 : hst1;
      float acc[4][4] = {};
#pragma unroll
      for (int bj = 0; bj < 4; ++bj) {
        const float* hr = hbase + (bg * 4 + bj) * HSTRIDE + ks * 36;
#pragma unroll
        for (int kk = 0; kk < 8; ++kk) {
          const float4 h4 = *(const float4*)(hr + kk * 4);
#pragma unroll
          for (int ci = 0; ci < 4; ++ci) {
            const float4 wv = w[ci][kk];
            acc[ci][bj] = fmaf(wv.x, h4.x, acc[ci][bj]);
            acc[ci][bj] = fmaf(wv.y, h4.y, acc[ci][bj]);
            acc[ci][bj] = fmaf(wv.z, h4.z, acc[ci][bj]);
            acc[ci][bj] = fmaf(wv.w, h4.w, acc[ci][bj]);
          }
        }
      }
#pragma unroll
      for (int ci = 0; ci < 4; ++ci)
#pragma unroll
        for (int bj = 0; bj < 4; ++bj)
          part[((bg * 4 + bj) * 8 + cg * 4 + ci) * 36 + m * 16 + ks] = acc[ci][bj];
      __syncthreads();
      if (st < 128) {
        const float4* pp = (const float4*)&part[st * 36];
        float sv = fbias;
#pragma unroll
        for (int j = 0; j < 8; ++j) {
          const float4 p = pp[j];
          sv += ((p.x + p.y) + (p.z + p.w));
        }
        const float hv = tanhf(sv);
        __hip_atomic_store((unsigned*)(h1b + (t & 1) * 16384 + (size_t)fb * HD + fcol),
                           __builtin_bit_cast(unsigned, hv),
                           __ATOMIC_RELAXED, __HIP_MEMORY_SCOPE_AGENT);
        outbuf[((size_t)fb * LS + t) * HD + fcol] = hv;
        if (t == LS - 1) outbuf[OUT0 + NB * HD + (size_t)fb * HD + fcol] = hv;  // h_final L1
      }
      __syncthreads();
      if (tid == 0)
        __hip_atomic_store(stampL1 + cb2, (unsigned)(t + 1),
                           __ATOMIC_RELAXED, __HIP_MEMORY_SCOPE_AGENT);
    }
  }
}

// ---------------------------------------------------------------------------
// ws layout (floats): [0,65536) h dbufs; [65536,65536+786432) WT;
// [SYNC_OFF, SYNC_OFF+256) per-block progress stamps (u32, 128 used).
// ---------------------------------------------------------------------------
extern "C" void kernel_launch(void* const* d_in, const int* in_sizes, int n_in,
                              void* d_out, int out_size, void* d_ws, size_t ws_size,
                              hipStream_t stream) {
  const float* x  = (const float*)d_in[0];
  const float* h0 = (const float*)d_in[1];
  const float* Wi = (const float*)d_in[2];
  const float* bi = (const float*)d_in[3];
  const float* Wh = (const float*)d_in[4];
  const float* bh = (const float*)d_in[5];
  float* out = (float*)d_out;
  float* ws  = (float*)d_ws;

  const float* Wi0 = Wi;
  const float* Wi1 = Wi + (size_t)HD * HD;
  const float* bi0 = bi;
  const float* bi1 = bi + HD;
  const float* Wh0 = Wh;
  const float* Wh1 = Wh + (size_t)HD * HD;
  const float* bh0 = bh;
  const float* bh1 = bh + HD;

  const float* WT = ws + 65536;

  static int attr_set = 0;
  if (!attr_set) {
    hipFuncSetAttribute((const void*)rnn_persist,
                        hipFuncAttributeMaxDynamicSharedMemorySize, SMEM_BYTES);
    attr_set = 1;
  }

  xi_gemm<<<dim3(8, 1024), 256, 0, stream>>>(x, Wi0, bi0, out);
  transpose_w<<<dim3(2, 512, 3), 256, 0, stream>>>(Wh0, Wi1, Wh1, ws + 65536);
  init_h<<<128, 256, 0, stream>>>(h0, ws);

  void* kargs[] = {(void*)&WT, (void*)&bh0, (void*)&bi1, (void*)&bh1,
                   (void*)&out, (void*)&ws};
  hipLaunchCooperativeKernel((const void*)rnn_persist, dim3(128), dim3(512),
                             kargs, SMEM_BYTES, stream);
}